// Round 1
// baseline (663.438 us; speedup 1.0000x reference)
//
#include <hip/hip_runtime.h>
#include <hip/hip_bf16.h>

// GCN: 2x (GEMM 128x128 -> normalized gather/scatter aggregate -> +bias,relu)
// then GEMM 128x16 + bias. Aggregation done gather-side via CSR-by-dst
// (built on device every launch: histogram + scan + bucket fill).
// Workspace layout: deg, scan partials, rowstart, cursor, colidx[E],
// dinv[n], bufA[n*128], bufB[n*128]  (~58 MB total).

#define WAVE 64

// ---------------- CSR build ----------------

__global__ __launch_bounds__(256) void count_deg(const int* __restrict__ dst,
                                                 int* __restrict__ deg, int E) {
    int i = blockIdx.x * 256 + threadIdx.x;
    if (i < E) atomicAdd(&deg[dst[i]], 1);
}

__global__ __launch_bounds__(256) void compute_dinv(const int* __restrict__ deg,
                                                    float* __restrict__ dinv, int n) {
    int i = blockIdx.x * 256 + threadIdx.x;
    if (i < n) dinv[i] = rsqrtf((float)(deg[i] + 1));  // +1 self-loop; always > 0
}

__global__ __launch_bounds__(256) void block_sum(const int* __restrict__ deg,
                                                 int* __restrict__ part, int n) {
    __shared__ int s[256];
    int t = threadIdx.x;
    int i = blockIdx.x * 256 + t;
    s[t] = (i < n) ? deg[i] : 0;
    __syncthreads();
    for (int d = 128; d > 0; d >>= 1) {
        if (t < d) s[t] += s[t + d];
        __syncthreads();
    }
    if (t == 0) part[blockIdx.x] = s[0];
}

// single block: exclusive-scan the per-block partials (nb <= 256)
__global__ __launch_bounds__(256) void scan_part(int* __restrict__ part, int nb) {
    __shared__ int s[256];
    int t = threadIdx.x;
    int v = (t < nb) ? part[t] : 0;
    s[t] = v;
    __syncthreads();
    for (int d = 1; d < 256; d <<= 1) {
        int x = (t >= d) ? s[t - d] : 0;
        __syncthreads();
        s[t] += x;
        __syncthreads();
    }
    if (t < nb) part[t] = s[t] - v;  // exclusive
}

__global__ __launch_bounds__(256) void scan_final(const int* __restrict__ deg,
                                                  const int* __restrict__ part,
                                                  int* __restrict__ rowstart,
                                                  int* __restrict__ cursor, int n, int E) {
    __shared__ int s[256];
    int t = threadIdx.x;
    int i = blockIdx.x * 256 + t;
    int v = (i < n) ? deg[i] : 0;
    s[t] = v;
    __syncthreads();
    for (int d = 1; d < 256; d <<= 1) {
        int x = (t >= d) ? s[t - d] : 0;
        __syncthreads();
        s[t] += x;
        __syncthreads();
    }
    int ex = s[t] - v + part[blockIdx.x];
    if (i < n) { rowstart[i] = ex; cursor[i] = ex; }
    if (i == 0 && blockIdx.x == 0) rowstart[n] = E;
}

__global__ __launch_bounds__(256) void fill_csr(const int* __restrict__ src,
                                                const int* __restrict__ dst,
                                                int* __restrict__ cursor,
                                                int* __restrict__ colidx, int E) {
    int i = blockIdx.x * 256 + threadIdx.x;
    if (i < E) {
        int p = atomicAdd(&cursor[dst[i]], 1);
        colidx[p] = src[i];
    }
}

// ---------------- GEMM n x 128 @ 128 x 128 (fp32 vector ALU) ----------------
// block 256 = 16x16 threads; tile 64 rows x 128 cols; thread: 4 rows x 8 cols
// (two float4 col groups at tx*4 and 64+tx*4 -> 2-way LDS bank alias = free).
__global__ __launch_bounds__(256) void gemm_nn128(const float* __restrict__ X,
                                                  const float* __restrict__ W,
                                                  float* __restrict__ Y, int n) {
    __shared__ float sW[128 * 128];  // 64 KB: full W in LDS
    const int tid = threadIdx.x;
    {
        const float4* W4 = (const float4*)W;
        float4* s4 = (float4*)sW;
#pragma unroll
        for (int i = 0; i < 16; ++i) s4[tid + 256 * i] = W4[tid + 256 * i];
    }
    __syncthreads();

    const int row0 = blockIdx.x * 64;
    const int ty = tid >> 4, tx = tid & 15;
    const int c0 = tx * 4;
    int r[4];
#pragma unroll
    for (int i = 0; i < 4; ++i) {
        int rr = row0 + ty * 4 + i;
        r[i] = rr < n ? rr : n - 1;  // clamp loads; stores guarded below
    }

    float acc[4][8];
#pragma unroll
    for (int i = 0; i < 4; ++i)
#pragma unroll
        for (int j = 0; j < 8; ++j) acc[i][j] = 0.f;

    for (int k4 = 0; k4 < 128; k4 += 4) {
        float a[4][4];
#pragma unroll
        for (int i = 0; i < 4; ++i)
            *(float4*)a[i] = *(const float4*)&X[(size_t)r[i] * 128 + k4];
#pragma unroll
        for (int kk = 0; kk < 4; ++kk) {
            const int k = k4 + kk;
            float4 w0 = *(const float4*)&sW[k * 128 + c0];
            float4 w1 = *(const float4*)&sW[k * 128 + 64 + c0];
            float wv[8] = {w0.x, w0.y, w0.z, w0.w, w1.x, w1.y, w1.z, w1.w};
#pragma unroll
            for (int i = 0; i < 4; ++i) {
                float av = a[i][kk];
#pragma unroll
                for (int j = 0; j < 8; ++j) acc[i][j] = fmaf(av, wv[j], acc[i][j]);
            }
        }
    }

#pragma unroll
    for (int i = 0; i < 4; ++i) {
        int rr = row0 + ty * 4 + i;
        if (rr < n) {
            float4 o0 = {acc[i][0], acc[i][1], acc[i][2], acc[i][3]};
            float4 o1 = {acc[i][4], acc[i][5], acc[i][6], acc[i][7]};
            *(float4*)&Y[(size_t)rr * 128 + c0] = o0;
            *(float4*)&Y[(size_t)rr * 128 + 64 + c0] = o1;
        }
    }
}

// ---------------- aggregate: one wave per destination node ----------------
// out[i] = relu( dinv[i] * ( dinv[i]*h[i] + sum_e dinv[col]*h[col] ) + b )
// Each of 64 lanes owns a float2 (128 cols) -> 512B coalesced row read/edge.
__global__ __launch_bounds__(256) void aggregate(const float* __restrict__ H,
                                                 const int* __restrict__ rowstart,
                                                 const int* __restrict__ colidx,
                                                 const float* __restrict__ dinv,
                                                 const float* __restrict__ bias,
                                                 float* __restrict__ O, int n,
                                                 int do_relu) {
    int wid = blockIdx.x * 4 + (threadIdx.x >> 6);  // 4 waves/block, 1 node/wave
    int lane = threadIdx.x & 63;
    if (wid >= n) return;

    const float2* H2 = (const float2*)H;
    float di = dinv[wid];
    float2 v = H2[(size_t)wid * 64 + lane];
    float ax = di * v.x, ay = di * v.y;  // self-loop term (outer di applied later)

    int s = rowstart[wid], e = rowstart[wid + 1];
    for (int p = s; p < e; ++p) {
        int c = colidx[p];
        float w = dinv[c];
        float2 u = H2[(size_t)c * 64 + lane];
        ax = fmaf(w, u.x, ax);
        ay = fmaf(w, u.y, ay);
    }

    const float2* b2 = (const float2*)bias;
    float2 bb = b2[lane];
    float ox = fmaf(ax, di, bb.x);
    float oy = fmaf(ay, di, bb.y);
    if (do_relu) {
        ox = ox > 0.f ? ox : 0.f;
        oy = oy > 0.f ? oy : 0.f;
    }
    float2 o = {ox, oy};
    ((float2*)O)[(size_t)wid * 64 + lane] = o;
}

// ---------------- final GEMM n x 128 @ 128 x 16 + bias ----------------
__global__ __launch_bounds__(256) void gemm_out16(const float* __restrict__ H,
                                                  const float* __restrict__ Wc,
                                                  const float* __restrict__ bc,
                                                  float* __restrict__ O, int n) {
    __shared__ float sW[128 * 16];   // 8 KB
    __shared__ float sH[16 * 132];   // padded stride 132 -> conflict-free column reads
    int tid = threadIdx.x;
    {
        const float4* W4 = (const float4*)Wc;
        float4* s4 = (float4*)sW;
        s4[tid] = W4[tid];
        s4[tid + 256] = W4[tid + 256];
    }
    int row0 = blockIdx.x * 16;
    for (int t = tid; t < 512; t += 256) {
        int r = t >> 5, kk = (t & 31) * 4;
        int rr = row0 + r;
        int rc = rr < n ? rr : n - 1;
        float4 v4 = *(const float4*)&H[(size_t)rc * 128 + kk];
        float* d = &sH[r * 132 + kk];
        d[0] = v4.x; d[1] = v4.y; d[2] = v4.z; d[3] = v4.w;
    }
    __syncthreads();

    int r = tid >> 4, c = tid & 15;
    float acc = 0.f;
#pragma unroll 4
    for (int k = 0; k < 128; ++k) acc = fmaf(sH[r * 132 + k], sW[k * 16 + c], acc);

    int rr = row0 + r;
    if (rr < n) O[(size_t)rr * 16 + c] = acc + bc[c];
}

// ---------------- launch ----------------

extern "C" void kernel_launch(void* const* d_in, const int* in_sizes, int n_in,
                              void* d_out, int out_size, void* d_ws, size_t ws_size,
                              hipStream_t stream) {
    const float* x  = (const float*)d_in[0];
    const int*   ei = (const int*)d_in[1];
    const float* W1 = (const float*)d_in[2];
    const float* b1 = (const float*)d_in[3];
    const float* W2 = (const float*)d_in[4];
    const float* b2 = (const float*)d_in[5];
    const float* Wc = (const float*)d_in[6];
    const float* bc = (const float*)d_in[7];
    float* out = (float*)d_out;

    const int n = in_sizes[0] / 128;  // 50000
    const int E = in_sizes[1] / 2;    // 1,600,000
    const int* src = ei;
    const int* dst = ei + E;

    char* p = (char*)d_ws;
    auto alloc = [&](size_t bytes) {
        char* q = p;
        p += (bytes + 255) & ~(size_t)255;
        return q;
    };
    int*   deg      = (int*)alloc((size_t)n * 4);
    int*   part     = (int*)alloc(4096);
    int*   rowstart = (int*)alloc(((size_t)n + 1) * 4);
    int*   cursor   = (int*)alloc((size_t)n * 4);
    int*   colidx   = (int*)alloc((size_t)E * 4);
    float* dinv     = (float*)alloc((size_t)n * 4);
    float* bufA     = (float*)alloc((size_t)n * 128 * 4);
    float* bufB     = (float*)alloc((size_t)n * 128 * 4);
    if ((size_t)(p - (char*)d_ws) > ws_size) return;  // scratch too small: bail cleanly

    hipMemsetAsync(deg, 0, (size_t)n * 4, stream);

    const int nb = (n + 255) / 256;      // 196 (<256, fits scan_part)
    const int eb = (E + 255) / 256;

    count_deg<<<eb, 256, 0, stream>>>(dst, deg, E);
    compute_dinv<<<nb, 256, 0, stream>>>(deg, dinv, n);
    block_sum<<<nb, 256, 0, stream>>>(deg, part, n);
    scan_part<<<1, 256, 0, stream>>>(part, nb);
    scan_final<<<nb, 256, 0, stream>>>(deg, part, rowstart, cursor, n, E);
    fill_csr<<<eb, 256, 0, stream>>>(src, dst, cursor, colidx, E);

    // layer 1
    gemm_nn128<<<(n + 63) / 64, 256, 0, stream>>>(x, W1, bufA, n);
    aggregate<<<(n + 3) / 4, 256, 0, stream>>>(bufA, rowstart, colidx, dinv, b1, bufB, n, 1);
    // layer 2
    gemm_nn128<<<(n + 63) / 64, 256, 0, stream>>>(bufB, W2, bufA, n);
    aggregate<<<(n + 3) / 4, 256, 0, stream>>>(bufA, rowstart, colidx, dinv, b2, bufB, n, 1);
    // classifier
    gemm_out16<<<(n + 15) / 16, 256, 0, stream>>>(bufB, Wc, bc, out, n);
}

// Round 2
// 535.704 us; speedup vs baseline: 1.2384x; 1.2384x over previous
//
#include <hip/hip_runtime.h>
#include <hip/hip_bf16.h>

// GCN on MI355X. Pipeline:
//   CSR-by-dst build (histogram + scan + bucket fill)
//   gemm128<fp32 A>  : x @ W1 -> bufA (bf16)
//   aggregate_mid    : normalized gather-sum + bias + relu -> bufB (bf16)
//   gemm128<bf16 A>  : bufB @ W2 -> bufA (bf16)
//   aggregate_out    : gather-sum + bias + relu fused with @Wc + bc -> out (fp32)
// h stored bf16 (256 B/row gather instead of 512 B) — accumulation is fp32.

typedef unsigned int uint;

static __device__ __forceinline__ unsigned short f2bf(float f) {
    unsigned u = __float_as_uint(f);
    u += 0x7fffu + ((u >> 16) & 1u);   // round-to-nearest-even
    return (unsigned short)(u >> 16);
}
static __device__ __forceinline__ uint pack2(float a, float b) {
    return (uint)f2bf(a) | ((uint)f2bf(b) << 16);
}
static __device__ __forceinline__ float lo2f(uint u) { return __uint_as_float(u << 16); }
static __device__ __forceinline__ float hi2f(uint u) { return __uint_as_float(u & 0xffff0000u); }

// ---------------- CSR build ----------------

__global__ __launch_bounds__(256) void count_deg(const int* __restrict__ dst,
                                                 int* __restrict__ deg, int E) {
    int i = blockIdx.x * 256 + threadIdx.x;
    if (i < E) atomicAdd(&deg[dst[i]], 1);
}

// fused: dinv = rsqrt(deg+1)  +  per-block partial sums of deg
__global__ __launch_bounds__(256) void deg_stats(const int* __restrict__ deg,
                                                 float* __restrict__ dinv,
                                                 int* __restrict__ part, int n) {
    __shared__ int s[256];
    int t = threadIdx.x;
    int i = blockIdx.x * 256 + t;
    int d = (i < n) ? deg[i] : 0;
    if (i < n) dinv[i] = rsqrtf((float)(d + 1));  // +1 self-loop
    s[t] = d;
    __syncthreads();
    for (int w = 128; w > 0; w >>= 1) {
        if (t < w) s[t] += s[t + w];
        __syncthreads();
    }
    if (t == 0) part[blockIdx.x] = s[0];
}

// single block: exclusive-scan per-block partials (nb <= 256)
__global__ __launch_bounds__(256) void scan_part(int* __restrict__ part, int nb) {
    __shared__ int s[256];
    int t = threadIdx.x;
    int v = (t < nb) ? part[t] : 0;
    s[t] = v;
    __syncthreads();
    for (int d = 1; d < 256; d <<= 1) {
        int x = (t >= d) ? s[t - d] : 0;
        __syncthreads();
        s[t] += x;
        __syncthreads();
    }
    if (t < nb) part[t] = s[t] - v;  // exclusive
}

__global__ __launch_bounds__(256) void scan_final(const int* __restrict__ deg,
                                                  const int* __restrict__ part,
                                                  int* __restrict__ rowstart,
                                                  int* __restrict__ cursor, int n, int E) {
    __shared__ int s[256];
    int t = threadIdx.x;
    int i = blockIdx.x * 256 + t;
    int v = (i < n) ? deg[i] : 0;
    s[t] = v;
    __syncthreads();
    for (int d = 1; d < 256; d <<= 1) {
        int x = (t >= d) ? s[t - d] : 0;
        __syncthreads();
        s[t] += x;
        __syncthreads();
    }
    int ex = s[t] - v + part[blockIdx.x];
    if (i < n) { rowstart[i] = ex; cursor[i] = ex; }
    if (i == 0 && blockIdx.x == 0) rowstart[n] = E;
}

__global__ __launch_bounds__(256) void fill_csr(const int* __restrict__ src,
                                                const int* __restrict__ dst,
                                                int* __restrict__ cursor,
                                                int* __restrict__ colidx, int E) {
    int i = blockIdx.x * 256 + threadIdx.x;
    if (i < E) {
        int p = atomicAdd(&cursor[dst[i]], 1);
        colidx[p] = src[i];
    }
}

// ---------------- GEMM n x 128 @ 128 x 128, bf16 packed output ----------------
// block 256 = 16x16; tile 64 rows x 128 cols; thread: 4 rows x 8 cols.
// W staged in 32x128 (16 KB) chunks -> occupancy not LDS-bound.
template <bool A_BF16>
__global__ __launch_bounds__(256) void gemm128(const void* __restrict__ Xv,
                                               const float* __restrict__ W,
                                               uint* __restrict__ Yb, int n) {
    __shared__ float sW[32 * 128];  // 16 KB
    const int tid = threadIdx.x;
    const int row0 = blockIdx.x * 64;
    const int ty = tid >> 4, tx = tid & 15;
    const int c0 = tx * 4;
    int r[4];
#pragma unroll
    for (int i = 0; i < 4; ++i) {
        int rr = row0 + ty * 4 + i;
        r[i] = rr < n ? rr : n - 1;  // clamp loads; stores guarded
    }

    float acc[4][8];
#pragma unroll
    for (int i = 0; i < 4; ++i)
#pragma unroll
        for (int j = 0; j < 8; ++j) acc[i][j] = 0.f;

    for (int kc = 0; kc < 128; kc += 32) {
        __syncthreads();  // previous chunk fully consumed
        {
            const float4* W4 = (const float4*)(W + kc * 128);
            float4* s4 = (float4*)sW;
#pragma unroll
            for (int i = 0; i < 4; ++i) s4[tid + 256 * i] = W4[tid + 256 * i];
        }
        __syncthreads();

        for (int k4 = 0; k4 < 32; k4 += 4) {
            float a[4][4];
            if (A_BF16) {
                const uint2* X2 = (const uint2*)Xv;
#pragma unroll
                for (int i = 0; i < 4; ++i) {
                    uint2 u = X2[(size_t)r[i] * 32 + ((kc + k4) >> 2)];
                    a[i][0] = lo2f(u.x); a[i][1] = hi2f(u.x);
                    a[i][2] = lo2f(u.y); a[i][3] = hi2f(u.y);
                }
            } else {
                const float4* X4 = (const float4*)Xv;
#pragma unroll
                for (int i = 0; i < 4; ++i) {
                    float4 v = X4[(size_t)r[i] * 32 + ((kc + k4) >> 2)];
                    a[i][0] = v.x; a[i][1] = v.y; a[i][2] = v.z; a[i][3] = v.w;
                }
            }
#pragma unroll
            for (int kk = 0; kk < 4; ++kk) {
                const int k = k4 + kk;
                float4 w0 = *(const float4*)&sW[k * 128 + c0];
                float4 w1 = *(const float4*)&sW[k * 128 + 64 + c0];
                float wv[8] = {w0.x, w0.y, w0.z, w0.w, w1.x, w1.y, w1.z, w1.w};
#pragma unroll
                for (int i = 0; i < 4; ++i) {
                    float av = a[i][kk];
#pragma unroll
                    for (int j = 0; j < 8; ++j) acc[i][j] = fmaf(av, wv[j], acc[i][j]);
                }
            }
        }
    }

#pragma unroll
    for (int i = 0; i < 4; ++i) {
        int rr = row0 + ty * 4 + i;
        if (rr < n) {
            uint2 o0 = {pack2(acc[i][0], acc[i][1]), pack2(acc[i][2], acc[i][3])};
            uint2 o1 = {pack2(acc[i][4], acc[i][5]), pack2(acc[i][6], acc[i][7])};
            *(uint2*)&Yb[(size_t)rr * 64 + (c0 >> 1)] = o0;
            *(uint2*)&Yb[(size_t)rr * 64 + 32 + (c0 >> 1)] = o1;
        }
    }
}

// ---------------- aggregate (middle layer): one wave per node ----------------
// out[i] = relu( dinv_i*( dinv_i*h_i + sum_e dinv_c*h_c ) + b ), bf16 out.
// Lane owns 2 cols (one packed uint) -> 256 B coalesced row per edge.
// Unroll-by-4 for memory-level parallelism.
__global__ __launch_bounds__(256) void aggregate_mid(const uint* __restrict__ Hb,
                                                     const int* __restrict__ rowstart,
                                                     const int* __restrict__ colidx,
                                                     const float* __restrict__ dinv,
                                                     const float* __restrict__ bias,
                                                     uint* __restrict__ Ob, int n) {
    int wid = blockIdx.x * 4 + (threadIdx.x >> 6);
    int lane = threadIdx.x & 63;
    if (wid >= n) return;

    float di = dinv[wid];
    uint self = Hb[(size_t)wid * 64 + lane];
    float ax = di * lo2f(self), ay = di * hi2f(self);

    int s = rowstart[wid], e = rowstart[wid + 1];
    int p = s;
    for (; p + 4 <= e; p += 4) {
        int c0 = colidx[p], c1 = colidx[p + 1], c2 = colidx[p + 2], c3 = colidx[p + 3];
        float w0 = dinv[c0], w1 = dinv[c1], w2 = dinv[c2], w3 = dinv[c3];
        uint u0 = Hb[(size_t)c0 * 64 + lane];
        uint u1 = Hb[(size_t)c1 * 64 + lane];
        uint u2 = Hb[(size_t)c2 * 64 + lane];
        uint u3 = Hb[(size_t)c3 * 64 + lane];
        ax = fmaf(w0, lo2f(u0), ax); ay = fmaf(w0, hi2f(u0), ay);
        ax = fmaf(w1, lo2f(u1), ax); ay = fmaf(w1, hi2f(u1), ay);
        ax = fmaf(w2, lo2f(u2), ax); ay = fmaf(w2, hi2f(u2), ay);
        ax = fmaf(w3, lo2f(u3), ax); ay = fmaf(w3, hi2f(u3), ay);
    }
    for (; p < e; ++p) {
        int c = colidx[p];
        float w = dinv[c];
        uint u = Hb[(size_t)c * 64 + lane];
        ax = fmaf(w, lo2f(u), ax); ay = fmaf(w, hi2f(u), ay);
    }

    float2 bb = ((const float2*)bias)[lane];
    float ox = fmaxf(fmaf(ax, di, bb.x), 0.f);
    float oy = fmaxf(fmaf(ay, di, bb.y), 0.f);
    Ob[(size_t)wid * 64 + lane] = pack2(ox, oy);
}

// ---------------- aggregate (final) fused with classifier ----------------
// a2 = relu(aggregate + b2); out = a2 @ Wc + bc (16 cols) — per-wave butterfly.
__global__ __launch_bounds__(256) void aggregate_out(const uint* __restrict__ Hb,
                                                     const int* __restrict__ rowstart,
                                                     const int* __restrict__ colidx,
                                                     const float* __restrict__ dinv,
                                                     const float* __restrict__ bias,
                                                     const float* __restrict__ Wc,
                                                     const float* __restrict__ bc,
                                                     float* __restrict__ out, int n) {
    __shared__ float sWcT[16 * 128];  // transposed: sWcT[c*128 + k], 8 KB
    int tid = threadIdx.x;
    for (int t = tid; t < 2048; t += 256) {
        int c = t >> 7, k = t & 127;
        sWcT[t] = Wc[k * 16 + c];
    }
    __syncthreads();

    int wid = blockIdx.x * 4 + (threadIdx.x >> 6);
    int lane = threadIdx.x & 63;
    if (wid >= n) return;

    float di = dinv[wid];
    uint self = Hb[(size_t)wid * 64 + lane];
    float ax = di * lo2f(self), ay = di * hi2f(self);

    int s = rowstart[wid], e = rowstart[wid + 1];
    int p = s;
    for (; p + 4 <= e; p += 4) {
        int c0 = colidx[p], c1 = colidx[p + 1], c2 = colidx[p + 2], c3 = colidx[p + 3];
        float w0 = dinv[c0], w1 = dinv[c1], w2 = dinv[c2], w3 = dinv[c3];
        uint u0 = Hb[(size_t)c0 * 64 + lane];
        uint u1 = Hb[(size_t)c1 * 64 + lane];
        uint u2 = Hb[(size_t)c2 * 64 + lane];
        uint u3 = Hb[(size_t)c3 * 64 + lane];
        ax = fmaf(w0, lo2f(u0), ax); ay = fmaf(w0, hi2f(u0), ay);
        ax = fmaf(w1, lo2f(u1), ax); ay = fmaf(w1, hi2f(u1), ay);
        ax = fmaf(w2, lo2f(u2), ax); ay = fmaf(w2, hi2f(u2), ay);
        ax = fmaf(w3, lo2f(u3), ax); ay = fmaf(w3, hi2f(u3), ay);
    }
    for (; p < e; ++p) {
        int c = colidx[p];
        float w = dinv[c];
        uint u = Hb[(size_t)c * 64 + lane];
        ax = fmaf(w, lo2f(u), ax); ay = fmaf(w, hi2f(u), ay);
    }

    float2 bb = ((const float2*)bias)[lane];
    float f0 = fmaxf(fmaf(ax, di, bb.x), 0.f);  // col k0 = 2*lane
    float f1 = fmaxf(fmaf(ay, di, bb.y), 0.f);  // col k1 = 2*lane+1

    const int k0 = 2 * lane;
    float pr[16];
#pragma unroll
    for (int c = 0; c < 16; ++c)
        pr[c] = f0 * sWcT[c * 128 + k0] + f1 * sWcT[c * 128 + k0 + 1];
#pragma unroll
    for (int m = 1; m < 64; m <<= 1) {
#pragma unroll
        for (int c = 0; c < 16; ++c) pr[c] += __shfl_xor(pr[c], m, 64);
    }
    if (lane == 0) {
        float* o = &out[(size_t)wid * 16];
#pragma unroll
        for (int c = 0; c < 16; ++c) o[c] = pr[c] + bc[c];
    }
}

// ---------------- launch ----------------

extern "C" void kernel_launch(void* const* d_in, const int* in_sizes, int n_in,
                              void* d_out, int out_size, void* d_ws, size_t ws_size,
                              hipStream_t stream) {
    const float* x  = (const float*)d_in[0];
    const int*   ei = (const int*)d_in[1];
    const float* W1 = (const float*)d_in[2];
    const float* b1 = (const float*)d_in[3];
    const float* W2 = (const float*)d_in[4];
    const float* b2 = (const float*)d_in[5];
    const float* Wc = (const float*)d_in[6];
    const float* bc = (const float*)d_in[7];
    float* out = (float*)d_out;

    const int n = in_sizes[0] / 128;  // 50000
    const int E = in_sizes[1] / 2;    // 1,600,000
    const int* src = ei;
    const int* dst = ei + E;

    char* p = (char*)d_ws;
    auto alloc = [&](size_t bytes) {
        char* q = p;
        p += (bytes + 255) & ~(size_t)255;
        return q;
    };
    int*   deg      = (int*)alloc((size_t)n * 4);
    int*   part     = (int*)alloc(4096);
    int*   rowstart = (int*)alloc(((size_t)n + 1) * 4);
    int*   cursor   = (int*)alloc((size_t)n * 4);
    int*   colidx   = (int*)alloc((size_t)E * 4);
    float* dinv     = (float*)alloc((size_t)n * 4);
    uint*  bufA     = (uint*)alloc((size_t)n * 64 * 4);  // bf16 h, packed 2/uint
    uint*  bufB     = (uint*)alloc((size_t)n * 64 * 4);
    if ((size_t)(p - (char*)d_ws) > ws_size) return;

    hipMemsetAsync(deg, 0, (size_t)n * 4, stream);

    const int nb = (n + 255) / 256;  // 196
    const int eb = (E + 255) / 256;

    count_deg<<<eb, 256, 0, stream>>>(dst, deg, E);
    deg_stats<<<nb, 256, 0, stream>>>(deg, dinv, part, n);
    scan_part<<<1, 256, 0, stream>>>(part, nb);
    scan_final<<<nb, 256, 0, stream>>>(deg, part, rowstart, cursor, n, E);
    fill_csr<<<eb, 256, 0, stream>>>(src, dst, cursor, colidx, E);

    // layer 1: x fp32 -> h1 bf16
    gemm128<false><<<(n + 63) / 64, 256, 0, stream>>>(x, W1, bufA, n);
    aggregate_mid<<<(n + 3) / 4, 256, 0, stream>>>(bufA, rowstart, colidx, dinv, b1, bufB, n);
    // layer 2: a1 bf16 -> h2 bf16
    gemm128<true><<<(n + 63) / 64, 256, 0, stream>>>(bufB, W2, bufA, n);
    // aggregate + classifier fused
    aggregate_out<<<(n + 3) / 4, 256, 0, stream>>>(bufA, rowstart, colidx, dinv, b2, Wc, bc, out, n);
}

// Round 3
// 379.032 us; speedup vs baseline: 1.7503x; 1.4133x over previous
//
#include <hip/hip_runtime.h>
#include <hip/hip_bf16.h>

// GCN on MI355X. Pipeline:
//   CSR-by-dst via two-level bucket binning (no random 4B scatter to HBM):
//     bucket_hist -> scan196 -> bin_edges (coarse, LDS-staged) -> build_rows
//     (fine, per-bucket L2-resident scatter; also produces deg/dinv/rowstart)
//   gemm128<fp32 A>  : x @ W1 -> bufA (bf16)
//   aggregate_mid    : normalized gather-sum + bias + relu -> bufB (bf16)
//   gemm128<bf16 A>  : bufB @ W2 -> bufA (bf16)
//   aggregate_out    : gather-sum + bias + relu fused with @Wc + bc -> out (fp32)
// h stored bf16 (256 B/row gather); accumulation fp32.
// Requires n <= 65536 (bucket count <= 256). Here n = 50000.

typedef unsigned int uint;

#define NPB 256                 // nodes per bucket
#define MAXBKT 256              // max buckets supported (n <= 65536)

static __device__ __forceinline__ unsigned short f2bf(float f) {
    unsigned u = __float_as_uint(f);
    u += 0x7fffu + ((u >> 16) & 1u);   // round-to-nearest-even
    return (unsigned short)(u >> 16);
}
static __device__ __forceinline__ uint pack2(float a, float b) {
    return (uint)f2bf(a) | ((uint)f2bf(b) << 16);
}
static __device__ __forceinline__ float lo2f(uint u) { return __uint_as_float(u << 16); }
static __device__ __forceinline__ float hi2f(uint u) { return __uint_as_float(u & 0xffff0000u); }

// ---------------- CSR build (bucketed) ----------------

// coarse histogram: how many edges land in each 256-node bucket
__global__ __launch_bounds__(256) void bucket_hist(const int* __restrict__ dst,
                                                   int* __restrict__ bcount,
                                                   int E, int nbuckets) {
    __shared__ int h[MAXBKT];
    int tid = threadIdx.x;
    h[tid] = 0;
    __syncthreads();
    int chunk = (E + gridDim.x - 1) / gridDim.x;
    int i0 = blockIdx.x * chunk;
    int i1 = min(E, i0 + chunk);
    for (int i = i0 + tid; i < i1; i += 256) atomicAdd(&h[dst[i] >> 8], 1);
    __syncthreads();
    if (tid < nbuckets && h[tid]) atomicAdd(&bcount[tid], h[tid]);
}

// single block: exclusive scan of bucket counts -> base + cursor copies
__global__ __launch_bounds__(256) void scan196(const int* __restrict__ bcount,
                                               int* __restrict__ bbase,
                                               int* __restrict__ bcursor,
                                               int nbuckets, int E) {
    __shared__ int s[MAXBKT];
    int t = threadIdx.x;
    int v = (t < nbuckets) ? bcount[t] : 0;
    s[t] = v;
    __syncthreads();
    for (int d = 1; d < 256; d <<= 1) {
        int x = (t >= d) ? s[t - d] : 0;
        __syncthreads();
        s[t] += x;
        __syncthreads();
    }
    if (t < nbuckets) {
        int ex = s[t] - v;
        bbase[t] = ex;
        bcursor[t] = ex;
    }
    if (t == 0) bbase[nbuckets] = E;
}

// coarse binning: payload = src (24b) | dstlocal (8b) appended per-bucket.
// Per block: LDS hist over chunk -> one reservation atomic per bucket ->
// sequential writes within each bucket stream (write-friendly).
__global__ __launch_bounds__(256) void bin_edges(const int* __restrict__ src,
                                                 const int* __restrict__ dst,
                                                 int* __restrict__ bcursor,
                                                 uint* __restrict__ pay,
                                                 int E, int nbuckets) {
    __shared__ int h[MAXBKT];
    __shared__ int base[MAXBKT];
    int tid = threadIdx.x;
    h[tid] = 0;
    __syncthreads();
    int chunk = (E + gridDim.x - 1) / gridDim.x;
    int i0 = blockIdx.x * chunk;
    int i1 = min(E, i0 + chunk);
    for (int i = i0 + tid; i < i1; i += 256) atomicAdd(&h[dst[i] >> 8], 1);
    __syncthreads();
    if (tid < nbuckets) base[tid] = h[tid] ? atomicAdd(&bcursor[tid], h[tid]) : 0;
    __syncthreads();
    h[tid] = 0;
    __syncthreads();
    for (int i = i0 + tid; i < i1; i += 256) {
        int d = dst[i];
        int b = d >> 8;
        int pos = base[b] + atomicAdd(&h[b], 1);
        pay[pos] = (uint)src[i] | ((uint)(d & 255) << 24);
    }
}

// fine pass: one block per bucket. LDS hist of dstlocal == node degrees ->
// dinv + rowstart; then scatter colidx within the bucket's (L2-resident) range.
__global__ __launch_bounds__(256) void build_rows(const uint* __restrict__ pay,
                                                  const int* __restrict__ bbase,
                                                  int* __restrict__ rowstart,
                                                  float* __restrict__ dinv,
                                                  int* __restrict__ colidx,
                                                  int n, int E, int nbuckets) {
    __shared__ int hist[NPB];
    __shared__ int sc[NPB];
    __shared__ int cur[NPB];
    int tid = threadIdx.x;
    int b = blockIdx.x;
    int node0 = b * NPB;
    int s = bbase[b], e = bbase[b + 1];

    hist[tid] = 0;
    __syncthreads();
    for (int i = s + tid; i < e; i += 256) atomicAdd(&hist[pay[i] >> 24], 1);
    __syncthreads();

    int v = hist[tid];
    sc[tid] = v;
    __syncthreads();
    for (int d = 1; d < 256; d <<= 1) {
        int x = (tid >= d) ? sc[tid - d] : 0;
        __syncthreads();
        sc[tid] += x;
        __syncthreads();
    }
    int excl = sc[tid] - v;
    cur[tid] = s + excl;
    int node = node0 + tid;
    if (node < n) {
        rowstart[node] = s + excl;
        dinv[node] = rsqrtf((float)(v + 1));  // +1 self-loop
    }
    if (b == nbuckets - 1 && tid == 0) rowstart[n] = E;
    __syncthreads();

    for (int i = s + tid; i < e; i += 256) {
        uint p = pay[i];
        int pos = atomicAdd(&cur[p >> 24], 1);
        colidx[pos] = (int)(p & 0xffffffu);
    }
}

// ---------------- GEMM n x 128 @ 128 x 128, bf16 packed output ----------------
template <bool A_BF16>
__global__ __launch_bounds__(256) void gemm128(const void* __restrict__ Xv,
                                               const float* __restrict__ W,
                                               uint* __restrict__ Yb, int n) {
    __shared__ float sW[32 * 128];  // 16 KB
    const int tid = threadIdx.x;
    const int row0 = blockIdx.x * 64;
    const int ty = tid >> 4, tx = tid & 15;
    const int c0 = tx * 4;
    int r[4];
#pragma unroll
    for (int i = 0; i < 4; ++i) {
        int rr = row0 + ty * 4 + i;
        r[i] = rr < n ? rr : n - 1;  // clamp loads; stores guarded
    }

    float acc[4][8];
#pragma unroll
    for (int i = 0; i < 4; ++i)
#pragma unroll
        for (int j = 0; j < 8; ++j) acc[i][j] = 0.f;

    for (int kc = 0; kc < 128; kc += 32) {
        __syncthreads();
        {
            const float4* W4 = (const float4*)(W + kc * 128);
            float4* s4 = (float4*)sW;
#pragma unroll
            for (int i = 0; i < 4; ++i) s4[tid + 256 * i] = W4[tid + 256 * i];
        }
        __syncthreads();

        for (int k4 = 0; k4 < 32; k4 += 4) {
            float a[4][4];
            if (A_BF16) {
                const uint2* X2 = (const uint2*)Xv;
#pragma unroll
                for (int i = 0; i < 4; ++i) {
                    uint2 u = X2[(size_t)r[i] * 32 + ((kc + k4) >> 2)];
                    a[i][0] = lo2f(u.x); a[i][1] = hi2f(u.x);
                    a[i][2] = lo2f(u.y); a[i][3] = hi2f(u.y);
                }
            } else {
                const float4* X4 = (const float4*)Xv;
#pragma unroll
                for (int i = 0; i < 4; ++i) {
                    float4 vv = X4[(size_t)r[i] * 32 + ((kc + k4) >> 2)];
                    a[i][0] = vv.x; a[i][1] = vv.y; a[i][2] = vv.z; a[i][3] = vv.w;
                }
            }
#pragma unroll
            for (int kk = 0; kk < 4; ++kk) {
                const int k = k4 + kk;
                float4 w0 = *(const float4*)&sW[k * 128 + c0];
                float4 w1 = *(const float4*)&sW[k * 128 + 64 + c0];
                float wv[8] = {w0.x, w0.y, w0.z, w0.w, w1.x, w1.y, w1.z, w1.w};
#pragma unroll
                for (int i = 0; i < 4; ++i) {
                    float av = a[i][kk];
#pragma unroll
                    for (int j = 0; j < 8; ++j) acc[i][j] = fmaf(av, wv[j], acc[i][j]);
                }
            }
        }
    }

#pragma unroll
    for (int i = 0; i < 4; ++i) {
        int rr = row0 + ty * 4 + i;
        if (rr < n) {
            uint2 o0 = {pack2(acc[i][0], acc[i][1]), pack2(acc[i][2], acc[i][3])};
            uint2 o1 = {pack2(acc[i][4], acc[i][5]), pack2(acc[i][6], acc[i][7])};
            *(uint2*)&Yb[(size_t)rr * 64 + (c0 >> 1)] = o0;
            *(uint2*)&Yb[(size_t)rr * 64 + 32 + (c0 >> 1)] = o1;
        }
    }
}

// ---------------- aggregate (middle layer): one wave per node ----------------
__global__ __launch_bounds__(256) void aggregate_mid(const uint* __restrict__ Hb,
                                                     const int* __restrict__ rowstart,
                                                     const int* __restrict__ colidx,
                                                     const float* __restrict__ dinv,
                                                     const float* __restrict__ bias,
                                                     uint* __restrict__ Ob, int n) {
    int wid = blockIdx.x * 4 + (threadIdx.x >> 6);
    int lane = threadIdx.x & 63;
    if (wid >= n) return;

    float di = dinv[wid];
    uint self = Hb[(size_t)wid * 64 + lane];
    float ax = di * lo2f(self), ay = di * hi2f(self);

    int s = rowstart[wid], e = rowstart[wid + 1];
    int p = s;
    for (; p + 4 <= e; p += 4) {
        int c0 = colidx[p], c1 = colidx[p + 1], c2 = colidx[p + 2], c3 = colidx[p + 3];
        float w0 = dinv[c0], w1 = dinv[c1], w2 = dinv[c2], w3 = dinv[c3];
        uint u0 = Hb[(size_t)c0 * 64 + lane];
        uint u1 = Hb[(size_t)c1 * 64 + lane];
        uint u2 = Hb[(size_t)c2 * 64 + lane];
        uint u3 = Hb[(size_t)c3 * 64 + lane];
        ax = fmaf(w0, lo2f(u0), ax); ay = fmaf(w0, hi2f(u0), ay);
        ax = fmaf(w1, lo2f(u1), ax); ay = fmaf(w1, hi2f(u1), ay);
        ax = fmaf(w2, lo2f(u2), ax); ay = fmaf(w2, hi2f(u2), ay);
        ax = fmaf(w3, lo2f(u3), ax); ay = fmaf(w3, hi2f(u3), ay);
    }
    for (; p < e; ++p) {
        int c = colidx[p];
        float w = dinv[c];
        uint u = Hb[(size_t)c * 64 + lane];
        ax = fmaf(w, lo2f(u), ax); ay = fmaf(w, hi2f(u), ay);
    }

    float2 bb = ((const float2*)bias)[lane];
    float ox = fmaxf(fmaf(ax, di, bb.x), 0.f);
    float oy = fmaxf(fmaf(ay, di, bb.y), 0.f);
    Ob[(size_t)wid * 64 + lane] = pack2(ox, oy);
}

// ---------------- aggregate (final) fused with classifier ----------------
__global__ __launch_bounds__(256) void aggregate_out(const uint* __restrict__ Hb,
                                                     const int* __restrict__ rowstart,
                                                     const int* __restrict__ colidx,
                                                     const float* __restrict__ dinv,
                                                     const float* __restrict__ bias,
                                                     const float* __restrict__ Wc,
                                                     const float* __restrict__ bc,
                                                     float* __restrict__ out, int n) {
    __shared__ float sWcT[16 * 128];  // transposed: sWcT[c*128 + k], 8 KB
    int tid = threadIdx.x;
    for (int t = tid; t < 2048; t += 256) {
        int c = t >> 7, k = t & 127;
        sWcT[t] = Wc[k * 16 + c];
    }
    __syncthreads();

    int wid = blockIdx.x * 4 + (threadIdx.x >> 6);
    int lane = threadIdx.x & 63;
    if (wid >= n) return;

    float di = dinv[wid];
    uint self = Hb[(size_t)wid * 64 + lane];
    float ax = di * lo2f(self), ay = di * hi2f(self);

    int s = rowstart[wid], e = rowstart[wid + 1];
    int p = s;
    for (; p + 4 <= e; p += 4) {
        int c0 = colidx[p], c1 = colidx[p + 1], c2 = colidx[p + 2], c3 = colidx[p + 3];
        float w0 = dinv[c0], w1 = dinv[c1], w2 = dinv[c2], w3 = dinv[c3];
        uint u0 = Hb[(size_t)c0 * 64 + lane];
        uint u1 = Hb[(size_t)c1 * 64 + lane];
        uint u2 = Hb[(size_t)c2 * 64 + lane];
        uint u3 = Hb[(size_t)c3 * 64 + lane];
        ax = fmaf(w0, lo2f(u0), ax); ay = fmaf(w0, hi2f(u0), ay);
        ax = fmaf(w1, lo2f(u1), ax); ay = fmaf(w1, hi2f(u1), ay);
        ax = fmaf(w2, lo2f(u2), ax); ay = fmaf(w2, hi2f(u2), ay);
        ax = fmaf(w3, lo2f(u3), ax); ay = fmaf(w3, hi2f(u3), ay);
    }
    for (; p < e; ++p) {
        int c = colidx[p];
        float w = dinv[c];
        uint u = Hb[(size_t)c * 64 + lane];
        ax = fmaf(w, lo2f(u), ax); ay = fmaf(w, hi2f(u), ay);
    }

    float2 bb = ((const float2*)bias)[lane];
    float f0 = fmaxf(fmaf(ax, di, bb.x), 0.f);  // col k0 = 2*lane
    float f1 = fmaxf(fmaf(ay, di, bb.y), 0.f);  // col k1 = 2*lane+1

    const int k0 = 2 * lane;
    float pr[16];
#pragma unroll
    for (int c = 0; c < 16; ++c)
        pr[c] = f0 * sWcT[c * 128 + k0] + f1 * sWcT[c * 128 + k0 + 1];
#pragma unroll
    for (int m = 1; m < 64; m <<= 1) {
#pragma unroll
        for (int c = 0; c < 16; ++c) pr[c] += __shfl_xor(pr[c], m, 64);
    }
    if (lane == 0) {
        float* o = &out[(size_t)wid * 16];
#pragma unroll
        for (int c = 0; c < 16; ++c) o[c] = pr[c] + bc[c];
    }
}

// ---------------- launch ----------------

extern "C" void kernel_launch(void* const* d_in, const int* in_sizes, int n_in,
                              void* d_out, int out_size, void* d_ws, size_t ws_size,
                              hipStream_t stream) {
    const float* x  = (const float*)d_in[0];
    const int*   ei = (const int*)d_in[1];
    const float* W1 = (const float*)d_in[2];
    const float* b1 = (const float*)d_in[3];
    const float* W2 = (const float*)d_in[4];
    const float* b2 = (const float*)d_in[5];
    const float* Wc = (const float*)d_in[6];
    const float* bc = (const float*)d_in[7];
    float* out = (float*)d_out;

    const int n = in_sizes[0] / 128;  // 50000
    const int E = in_sizes[1] / 2;    // 1,600,000
    const int* src = ei;
    const int* dst = ei + E;
    const int nbuckets = (n + NPB - 1) / NPB;  // 196 (requires n <= 65536)

    char* p = (char*)d_ws;
    auto alloc = [&](size_t bytes) {
        char* q = p;
        p += (bytes + 255) & ~(size_t)255;
        return q;
    };
    int*   bcount   = (int*)alloc(MAXBKT * 4);
    int*   bbase    = (int*)alloc((MAXBKT + 1) * 4);
    int*   bcursor  = (int*)alloc(MAXBKT * 4);
    int*   rowstart = (int*)alloc(((size_t)n + 1) * 4);
    int*   colidx   = (int*)alloc((size_t)E * 4);
    uint*  pay      = (uint*)alloc((size_t)E * 4);
    float* dinv     = (float*)alloc((size_t)n * 4);
    uint*  bufA     = (uint*)alloc((size_t)n * 64 * 4);  // bf16 h, packed 2/uint
    uint*  bufB     = (uint*)alloc((size_t)n * 64 * 4);
    if ((size_t)(p - (char*)d_ws) > ws_size) return;

    hipMemsetAsync(bcount, 0, MAXBKT * 4, stream);

    bucket_hist<<<256, 256, 0, stream>>>(dst, bcount, E, nbuckets);
    scan196<<<1, 256, 0, stream>>>(bcount, bbase, bcursor, nbuckets, E);
    bin_edges<<<256, 256, 0, stream>>>(src, dst, bcursor, pay, E, nbuckets);
    build_rows<<<nbuckets, 256, 0, stream>>>(pay, bbase, rowstart, dinv, colidx, n, E, nbuckets);

    // layer 1: x fp32 -> h1 bf16
    gemm128<false><<<(n + 63) / 64, 256, 0, stream>>>(x, W1, bufA, n);
    aggregate_mid<<<(n + 3) / 4, 256, 0, stream>>>(bufA, rowstart, colidx, dinv, b1, bufB, n);
    // layer 2: a1 bf16 -> h2 bf16
    gemm128<true><<<(n + 63) / 64, 256, 0, stream>>>(bufB, W2, bufA, n);
    // aggregate + classifier fused
    aggregate_out<<<(n + 3) / 4, 256, 0, stream>>>(bufA, rowstart, colidx, dinv, b2, Wc, bc, out, n);
}

// Round 4
// 327.056 us; speedup vs baseline: 2.0285x; 1.1589x over previous
//
#include <hip/hip_runtime.h>
#include <hip/hip_bf16.h>

// GCN on MI355X. Pipeline:
//   CSR-by-dst via two-level bucket binning (no random 4B scatter to HBM)
//   gemm128<fp32 A>  : x @ W1 -> bufA (bf16)
//   aggregate_mid    : gather-sum + bias + relu -> bufB (bf16)
//   gemm128<bf16 A>  : bufB @ W2 -> bufA (bf16)
//   aggregate_out    : gather-sum + bias + relu fused with @Wc + bc -> out
// Aggregates: 4 quarter-waves gather 4 edges/instruction (16B/lane),
// unroll x2 (8 edges in flight), cross-quarter shfl_xor reduce.
// h stored bf16 (256 B/row); accumulation fp32. Requires n <= 65536.

typedef unsigned int uint;

#define NPB 256                 // nodes per bucket
#define MAXBKT 256              // max buckets (n <= 65536)

static __device__ __forceinline__ unsigned short f2bf(float f) {
    unsigned u = __float_as_uint(f);
    u += 0x7fffu + ((u >> 16) & 1u);   // round-to-nearest-even
    return (unsigned short)(u >> 16);
}
static __device__ __forceinline__ uint pack2(float a, float b) {
    return (uint)f2bf(a) | ((uint)f2bf(b) << 16);
}
static __device__ __forceinline__ float lo2f(uint u) { return __uint_as_float(u << 16); }
static __device__ __forceinline__ float hi2f(uint u) { return __uint_as_float(u & 0xffff0000u); }

#define UNPACK8(dst, u)                                        \
    dst[0] = lo2f(u.x); dst[1] = hi2f(u.x);                    \
    dst[2] = lo2f(u.y); dst[3] = hi2f(u.y);                    \
    dst[4] = lo2f(u.z); dst[5] = hi2f(u.z);                    \
    dst[6] = lo2f(u.w); dst[7] = hi2f(u.w);

// ---------------- CSR build (bucketed) ----------------

__global__ __launch_bounds__(256) void bucket_hist(const int* __restrict__ dst,
                                                   int* __restrict__ bcount,
                                                   int E, int nbuckets) {
    __shared__ int h[MAXBKT];
    int tid = threadIdx.x;
    h[tid] = 0;
    __syncthreads();
    int chunk = (E + gridDim.x - 1) / gridDim.x;
    int i0 = blockIdx.x * chunk;
    int i1 = min(E, i0 + chunk);
    for (int i = i0 + tid; i < i1; i += 256) atomicAdd(&h[dst[i] >> 8], 1);
    __syncthreads();
    if (tid < nbuckets && h[tid]) atomicAdd(&bcount[tid], h[tid]);
}

__global__ __launch_bounds__(256) void scan196(const int* __restrict__ bcount,
                                               int* __restrict__ bbase,
                                               int* __restrict__ bcursor,
                                               int nbuckets, int E) {
    __shared__ int s[MAXBKT];
    int t = threadIdx.x;
    int v = (t < nbuckets) ? bcount[t] : 0;
    s[t] = v;
    __syncthreads();
    for (int d = 1; d < 256; d <<= 1) {
        int x = (t >= d) ? s[t - d] : 0;
        __syncthreads();
        s[t] += x;
        __syncthreads();
    }
    if (t < nbuckets) {
        int ex = s[t] - v;
        bbase[t] = ex;
        bcursor[t] = ex;
    }
    if (t == 0) bbase[nbuckets] = E;
}

__global__ __launch_bounds__(256) void bin_edges(const int* __restrict__ src,
                                                 const int* __restrict__ dst,
                                                 int* __restrict__ bcursor,
                                                 uint* __restrict__ pay,
                                                 int E, int nbuckets) {
    __shared__ int h[MAXBKT];
    __shared__ int base[MAXBKT];
    int tid = threadIdx.x;
    h[tid] = 0;
    __syncthreads();
    int chunk = (E + gridDim.x - 1) / gridDim.x;
    int i0 = blockIdx.x * chunk;
    int i1 = min(E, i0 + chunk);
    for (int i = i0 + tid; i < i1; i += 256) atomicAdd(&h[dst[i] >> 8], 1);
    __syncthreads();
    if (tid < nbuckets) base[tid] = h[tid] ? atomicAdd(&bcursor[tid], h[tid]) : 0;
    __syncthreads();
    h[tid] = 0;
    __syncthreads();
    for (int i = i0 + tid; i < i1; i += 256) {
        int d = dst[i];
        int b = d >> 8;
        int pos = base[b] + atomicAdd(&h[b], 1);
        pay[pos] = (uint)src[i] | ((uint)(d & 255) << 24);
    }
}

__global__ __launch_bounds__(256) void build_rows(const uint* __restrict__ pay,
                                                  const int* __restrict__ bbase,
                                                  int* __restrict__ rowstart,
                                                  float* __restrict__ dinv,
                                                  int* __restrict__ colidx,
                                                  int n, int E, int nbuckets) {
    __shared__ int hist[NPB];
    __shared__ int sc[NPB];
    __shared__ int cur[NPB];
    int tid = threadIdx.x;
    int b = blockIdx.x;
    int node0 = b * NPB;
    int s = bbase[b], e = bbase[b + 1];

    hist[tid] = 0;
    __syncthreads();
    for (int i = s + tid; i < e; i += 256) atomicAdd(&hist[pay[i] >> 24], 1);
    __syncthreads();

    int v = hist[tid];
    sc[tid] = v;
    __syncthreads();
    for (int d = 1; d < 256; d <<= 1) {
        int x = (tid >= d) ? sc[tid - d] : 0;
        __syncthreads();
        sc[tid] += x;
        __syncthreads();
    }
    int excl = sc[tid] - v;
    cur[tid] = s + excl;
    int node = node0 + tid;
    if (node < n) {
        rowstart[node] = s + excl;
        dinv[node] = rsqrtf((float)(v + 1));  // +1 self-loop
    }
    if (b == nbuckets - 1 && tid == 0) rowstart[n] = E;
    __syncthreads();

    for (int i = s + tid; i < e; i += 256) {
        uint p = pay[i];
        int pos = atomicAdd(&cur[p >> 24], 1);
        colidx[pos] = (int)(p & 0xffffffu);
    }
}

// ---------------- GEMM n x 128 @ 128 x 128, bf16 packed output ----------------
template <bool A_BF16>
__global__ __launch_bounds__(256) void gemm128(const void* __restrict__ Xv,
                                               const float* __restrict__ W,
                                               uint* __restrict__ Yb, int n) {
    __shared__ float sW[32 * 128];  // 16 KB
    const int tid = threadIdx.x;
    const int row0 = blockIdx.x * 64;
    const int ty = tid >> 4, tx = tid & 15;
    const int c0 = tx * 4;
    int r[4];
#pragma unroll
    for (int i = 0; i < 4; ++i) {
        int rr = row0 + ty * 4 + i;
        r[i] = rr < n ? rr : n - 1;
    }

    float acc[4][8];
#pragma unroll
    for (int i = 0; i < 4; ++i)
#pragma unroll
        for (int j = 0; j < 8; ++j) acc[i][j] = 0.f;

    for (int kc = 0; kc < 128; kc += 32) {
        __syncthreads();
        {
            const float4* W4 = (const float4*)(W + kc * 128);
            float4* s4 = (float4*)sW;
#pragma unroll
            for (int i = 0; i < 4; ++i) s4[tid + 256 * i] = W4[tid + 256 * i];
        }
        __syncthreads();

        for (int k4 = 0; k4 < 32; k4 += 4) {
            float a[4][4];
            if (A_BF16) {
                const uint2* X2 = (const uint2*)Xv;
#pragma unroll
                for (int i = 0; i < 4; ++i) {
                    uint2 u = X2[(size_t)r[i] * 32 + ((kc + k4) >> 2)];
                    a[i][0] = lo2f(u.x); a[i][1] = hi2f(u.x);
                    a[i][2] = lo2f(u.y); a[i][3] = hi2f(u.y);
                }
            } else {
                const float4* X4 = (const float4*)Xv;
#pragma unroll
                for (int i = 0; i < 4; ++i) {
                    float4 vv = X4[(size_t)r[i] * 32 + ((kc + k4) >> 2)];
                    a[i][0] = vv.x; a[i][1] = vv.y; a[i][2] = vv.z; a[i][3] = vv.w;
                }
            }
#pragma unroll
            for (int kk = 0; kk < 4; ++kk) {
                const int k = k4 + kk;
                float4 w0 = *(const float4*)&sW[k * 128 + c0];
                float4 w1 = *(const float4*)&sW[k * 128 + 64 + c0];
                float wv[8] = {w0.x, w0.y, w0.z, w0.w, w1.x, w1.y, w1.z, w1.w};
#pragma unroll
                for (int i = 0; i < 4; ++i) {
                    float av = a[i][kk];
#pragma unroll
                    for (int j = 0; j < 8; ++j) acc[i][j] = fmaf(av, wv[j], acc[i][j]);
                }
            }
        }
    }

#pragma unroll
    for (int i = 0; i < 4; ++i) {
        int rr = row0 + ty * 4 + i;
        if (rr < n) {
            uint2 o0 = {pack2(acc[i][0], acc[i][1]), pack2(acc[i][2], acc[i][3])};
            uint2 o1 = {pack2(acc[i][4], acc[i][5]), pack2(acc[i][6], acc[i][7])};
            *(uint2*)&Yb[(size_t)rr * 64 + (c0 >> 1)] = o0;
            *(uint2*)&Yb[(size_t)rr * 64 + 32 + (c0 >> 1)] = o1;
        }
    }
}

// ---------------- aggregate core: 4 edges / load instruction ----------------
// Wave = 4 quarters of 16 lanes. Quarter q gathers edge (base+q) with
// uint4 (16B/lane x 16 lanes = 256B row). Unroll x2: 8 edges in flight.
// Returns per-lane acc[8] (cols sub*8 .. sub*8+8), complete after
// cross-quarter shfl_xor(16|32).
static __device__ __forceinline__ void gather_acc(const uint4* __restrict__ Hb4,
                                                  const int* __restrict__ rowstart,
                                                  const int* __restrict__ colidx,
                                                  const float* __restrict__ dinv,
                                                  int wid, int q, int sub,
                                                  float di, float acc[8]) {
    uint4 su = Hb4[(size_t)wid * 16 + sub];
    float wS = (q == 0) ? di : 0.f;   // self-loop counted once
    float t[8];
    UNPACK8(t, su);
#pragma unroll
    for (int j = 0; j < 8; ++j) acc[j] = wS * t[j];

    int s = rowstart[wid], e = rowstart[wid + 1];
    for (int base = s; base < e; base += 8) {
        int pA = base + q, pB = base + 4 + q;
        int cA = (pA < e) ? colidx[pA] : wid;
        int cB = (pB < e) ? colidx[pB] : wid;
        float wA = (pA < e) ? dinv[cA] : 0.f;
        float wB = (pB < e) ? dinv[cB] : 0.f;
        uint4 uA = Hb4[(size_t)cA * 16 + sub];
        uint4 uB = Hb4[(size_t)cB * 16 + sub];
        float a[8], b[8];
        UNPACK8(a, uA);
        UNPACK8(b, uB);
#pragma unroll
        for (int j = 0; j < 8; ++j) acc[j] = fmaf(wA, a[j], acc[j]);
#pragma unroll
        for (int j = 0; j < 8; ++j) acc[j] = fmaf(wB, b[j], acc[j]);
    }
#pragma unroll
    for (int j = 0; j < 8; ++j) {
        acc[j] += __shfl_xor(acc[j], 16, 64);
        acc[j] += __shfl_xor(acc[j], 32, 64);
    }
}

// middle layer: + bias, relu, bf16 out
__global__ __launch_bounds__(256) void aggregate_mid(const uint* __restrict__ Hb,
                                                     const int* __restrict__ rowstart,
                                                     const int* __restrict__ colidx,
                                                     const float* __restrict__ dinv,
                                                     const float* __restrict__ bias,
                                                     uint* __restrict__ Ob, int n) {
    int wid = blockIdx.x * 4 + (threadIdx.x >> 6);
    int lane = threadIdx.x & 63;
    if (wid >= n) return;
    int q = lane >> 4, sub = lane & 15;
    float di = dinv[wid];
    float acc[8];
    gather_acc((const uint4*)Hb, rowstart, colidx, dinv, wid, q, sub, di, acc);

    if (q == 0) {
        float4 b0 = ((const float4*)bias)[sub * 2];
        float4 b1 = ((const float4*)bias)[sub * 2 + 1];
        float o0 = fmaxf(fmaf(acc[0], di, b0.x), 0.f);
        float o1 = fmaxf(fmaf(acc[1], di, b0.y), 0.f);
        float o2 = fmaxf(fmaf(acc[2], di, b0.z), 0.f);
        float o3 = fmaxf(fmaf(acc[3], di, b0.w), 0.f);
        float o4 = fmaxf(fmaf(acc[4], di, b1.x), 0.f);
        float o5 = fmaxf(fmaf(acc[5], di, b1.y), 0.f);
        float o6 = fmaxf(fmaf(acc[6], di, b1.z), 0.f);
        float o7 = fmaxf(fmaf(acc[7], di, b1.w), 0.f);
        uint4 o;
        o.x = pack2(o0, o1); o.y = pack2(o2, o3);
        o.z = pack2(o4, o5); o.w = pack2(o6, o7);
        ((uint4*)Ob)[(size_t)wid * 16 + sub] = o;
    }
}

// final layer fused with classifier: out = relu(agg + b2) @ Wc + bc
__global__ __launch_bounds__(256) void aggregate_out(const uint* __restrict__ Hb,
                                                     const int* __restrict__ rowstart,
                                                     const int* __restrict__ colidx,
                                                     const float* __restrict__ dinv,
                                                     const float* __restrict__ bias,
                                                     const float* __restrict__ Wc,
                                                     const float* __restrict__ bc,
                                                     float* __restrict__ out, int n) {
    __shared__ float sWc[128 * 16];  // natural [k][c] layout, 8 KB
    int tid = threadIdx.x;
    {
        const float4* W4 = (const float4*)Wc;
        float4* s4 = (float4*)sWc;
        s4[tid] = W4[tid];
        s4[tid + 256] = W4[tid + 256];
    }
    __syncthreads();

    int wid = blockIdx.x * 4 + (threadIdx.x >> 6);
    int lane = threadIdx.x & 63;
    if (wid >= n) return;
    int q = lane >> 4, sub = lane & 15;
    float di = dinv[wid];
    float acc[8];
    gather_acc((const uint4*)Hb, rowstart, colidx, dinv, wid, q, sub, di, acc);

    // f = relu(acc*di + b2) for cols k = sub*8..sub*8+8 (all lanes complete)
    float4 b0 = ((const float4*)bias)[sub * 2];
    float4 b1 = ((const float4*)bias)[sub * 2 + 1];
    float f[8];
    f[0] = fmaxf(fmaf(acc[0], di, b0.x), 0.f);
    f[1] = fmaxf(fmaf(acc[1], di, b0.y), 0.f);
    f[2] = fmaxf(fmaf(acc[2], di, b0.z), 0.f);
    f[3] = fmaxf(fmaf(acc[3], di, b0.w), 0.f);
    f[4] = fmaxf(fmaf(acc[4], di, b1.x), 0.f);
    f[5] = fmaxf(fmaf(acc[5], di, b1.y), 0.f);
    f[6] = fmaxf(fmaf(acc[6], di, b1.z), 0.f);
    f[7] = fmaxf(fmaf(acc[7], di, b1.w), 0.f);

    // quarter q computes output cols q*4..q*4+4 from its 8 k's.
    // sWc read: 16 subs broadcast one addr; 4 quarters hit 4 distinct banks.
    float pr[4] = {0.f, 0.f, 0.f, 0.f};
#pragma unroll
    for (int jj = 0; jj < 8; ++jj) {
        const float* wrow = &sWc[(sub * 8 + jj) * 16 + q * 4];
#pragma unroll
        for (int cc = 0; cc < 4; ++cc) pr[cc] = fmaf(f[jj], wrow[cc], pr[cc]);
    }
#pragma unroll
    for (int m = 1; m < 16; m <<= 1) {
#pragma unroll
        for (int cc = 0; cc < 4; ++cc) pr[cc] += __shfl_xor(pr[cc], m, 64);
    }
    if (sub == 0) {
        float4 bcq = ((const float4*)bc)[q];
        float4 o = {pr[0] + bcq.x, pr[1] + bcq.y, pr[2] + bcq.z, pr[3] + bcq.w};
        *(float4*)&out[(size_t)wid * 16 + q * 4] = o;
    }
}

// ---------------- launch ----------------

extern "C" void kernel_launch(void* const* d_in, const int* in_sizes, int n_in,
                              void* d_out, int out_size, void* d_ws, size_t ws_size,
                              hipStream_t stream) {
    const float* x  = (const float*)d_in[0];
    const int*   ei = (const int*)d_in[1];
    const float* W1 = (const float*)d_in[2];
    const float* b1 = (const float*)d_in[3];
    const float* W2 = (const float*)d_in[4];
    const float* b2 = (const float*)d_in[5];
    const float* Wc = (const float*)d_in[6];
    const float* bc = (const float*)d_in[7];
    float* out = (float*)d_out;

    const int n = in_sizes[0] / 128;  // 50000
    const int E = in_sizes[1] / 2;    // 1,600,000
    const int* src = ei;
    const int* dst = ei + E;
    const int nbuckets = (n + NPB - 1) / NPB;  // 196

    char* p = (char*)d_ws;
    auto alloc = [&](size_t bytes) {
        char* q = p;
        p += (bytes + 255) & ~(size_t)255;
        return q;
    };
    int*   bcount   = (int*)alloc(MAXBKT * 4);
    int*   bbase    = (int*)alloc((MAXBKT + 1) * 4);
    int*   bcursor  = (int*)alloc(MAXBKT * 4);
    int*   rowstart = (int*)alloc(((size_t)n + 1) * 4);
    int*   colidx   = (int*)alloc((size_t)E * 4);
    uint*  pay      = (uint*)alloc((size_t)E * 4);
    float* dinv     = (float*)alloc((size_t)n * 4);
    uint*  bufA     = (uint*)alloc((size_t)n * 64 * 4);  // bf16 h
    uint*  bufB     = (uint*)alloc((size_t)n * 64 * 4);
    if ((size_t)(p - (char*)d_ws) > ws_size) return;

    hipMemsetAsync(bcount, 0, MAXBKT * 4, stream);

    bucket_hist<<<256, 256, 0, stream>>>(dst, bcount, E, nbuckets);
    scan196<<<1, 256, 0, stream>>>(bcount, bbase, bcursor, nbuckets, E);
    bin_edges<<<256, 256, 0, stream>>>(src, dst, bcursor, pay, E, nbuckets);
    build_rows<<<nbuckets, 256, 0, stream>>>(pay, bbase, rowstart, dinv, colidx, n, E, nbuckets);

    gemm128<false><<<(n + 63) / 64, 256, 0, stream>>>(x, W1, bufA, n);
    aggregate_mid<<<(n + 3) / 4, 256, 0, stream>>>(bufA, rowstart, colidx, dinv, b1, bufB, n);
    gemm128<true><<<(n + 63) / 64, 256, 0, stream>>>(bufB, W2, bufA, n);
    aggregate_out<<<(n + 3) / 4, 256, 0, stream>>>(bufA, rowstart, colidx, dinv, b2, Wc, bc, out, n);
}